// Round 1
// baseline (14876.680 us; speedup 1.0000x reference)
//
#include <hip/hip_runtime.h>
#include <math.h>

#define BB 64
#define TT 32
#define ENCL 128
#define DD 800
#define CHN 8
#define RR 10
#define CCOL 10

__device__ __forceinline__ float sigf(float x) { return 1.0f / (1.0f + expf(-x)); }

// ---------------- ConvLSTM cell: one thread per (b, r, ch, col) -----------------
__global__ __launch_bounds__(256) void cell_kernel(
    const float* __restrict__ xin, int s, int cin_x,
    const float* __restrict__ h_old, const float* __restrict__ c_old,
    float* __restrict__ h_new, float* __restrict__ c_new,
    const float* __restrict__ cw, const float* __restrict__ cb)
{
    int tid = blockIdx.x * blockDim.x + threadIdx.x;
    if (tid >= BB * DD) return;
    const int col = tid % CCOL;
    const int ch  = (tid / CCOL) % CHN;
    const int r   = (tid / (CCOL * CHN)) % RR;
    const int b   = tid / (CCOL * CHN * RR);
    const int cin = cin_x + CHN;

    float g0 = cb[ch], g1 = cb[CHN + ch], g2 = cb[2 * CHN + ch], g3 = cb[3 * CHN + ch];

    for (int ic = 0; ic < cin; ++ic) {
        float z[3];
#pragma unroll
        for (int p = 0; p < 3; ++p) {
            int cc2 = col + p - 1;
            float v = 0.f;
            if (cc2 >= 0 && cc2 < CCOL) {
                if (ic < cin_x) {
                    v = (cin_x == 1)
                        ? xin[(b * TT + s) * 100 + r * CCOL + cc2]          // x_flat [B,T,100]
                        : xin[b * DD + r * (CHN * CCOL) + ic * CCOL + cc2]; // layer_io [B,800]
                } else {
                    v = h_old[b * DD + r * (CHN * CCOL) + (ic - cin_x) * CCOL + cc2];
                }
            }
            z[p] = v;
        }
        const float* w0 = cw + ((0 * CHN + ch) * cin + ic) * 3;
        const float* w1 = cw + ((1 * CHN + ch) * cin + ic) * 3;
        const float* w2 = cw + ((2 * CHN + ch) * cin + ic) * 3;
        const float* w3 = cw + ((3 * CHN + ch) * cin + ic) * 3;
        g0 += z[0] * w0[0] + z[1] * w0[1] + z[2] * w0[2];
        g1 += z[0] * w1[0] + z[1] * w1[1] + z[2] * w1[2];
        g2 += z[0] * w2[0] + z[1] * w2[1] + z[2] * w2[2];
        g3 += z[0] * w3[0] + z[1] * w3[1] + z[2] * w3[2];
    }
    float c2 = sigf(g1) * c_old[tid] + sigf(g0) * tanhf(g2);
    float hn = sigf(g3) * tanhf(c2);
    c_new[tid] = c2;
    h_new[tid] = hn;
}

// ---------------- inter attention: one block per b -----------------
__global__ __launch_bounds__(256) void inter_attn_kernel(
    const float* __restrict__ hq, const float* __restrict__ enc, float* __restrict__ ctx)
{
    const int b = blockIdx.x;
    const int tid = threadIdx.x;
    const int lane = tid & 63;
    const int wv = tid >> 6;
    __shared__ float hs[DD];
    __shared__ float sc[ENCL];
    for (int i = tid; i < DD; i += 256) hs[i] = hq[b * DD + i];
    __syncthreads();
    const float* eb = enc + (size_t)b * ENCL * DD;
    for (int le = wv; le < ENCL; le += 4) {
        const float* er = eb + le * DD;
        float sum = 0.f;
        for (int d = lane; d < DD; d += 64) sum += hs[d] * er[d];
#pragma unroll
        for (int off = 32; off > 0; off >>= 1) sum += __shfl_down(sum, off);
        if (lane == 0) sc[le] = sum;
    }
    __syncthreads();
    if (wv == 0) {
        float v0 = sc[lane], v1 = sc[64 + lane];
        float m = fmaxf(v0, v1);
#pragma unroll
        for (int off = 32; off > 0; off >>= 1) m = fmaxf(m, __shfl_xor(m, off));
        float e0 = expf(v0 - m), e1 = expf(v1 - m);
        float ss = e0 + e1;
#pragma unroll
        for (int off = 32; off > 0; off >>= 1) ss += __shfl_xor(ss, off);
        float inv = 1.f / ss;
        sc[lane] = e0 * inv;
        sc[64 + lane] = e1 * inv;
    }
    __syncthreads();
    for (int d = tid; d < DD; d += 256) {
        float sum = 0.f;
        for (int le = 0; le < ENCL; ++le) sum += sc[le] * eb[le * DD + d];
        ctx[b * DD + d] = sum;
    }
}

// ---------------- self attention (s>0): one block per b -----------------
__global__ __launch_bounds__(256) void self_attn_kernel(
    const float* __restrict__ hq, const float* __restrict__ pre,
    const float* __restrict__ ref, int s, float* __restrict__ ctx)
{
    const int b = blockIdx.x;
    const int tid = threadIdx.x;
    const int lane = tid & 63;
    const int wv = tid >> 6;
    __shared__ float hs[DD];
    __shared__ float sc[TT];
    for (int i = tid; i < DD; i += 256) hs[i] = hq[b * DD + i];
    __syncthreads();
    for (int t = wv; t < s; t += 4) {
        const float* pr = pre + ((size_t)t * BB + b) * DD;
        float sum = 0.f;
        for (int d = lane; d < DD; d += 64) sum += hs[d] * pr[d];
#pragma unroll
        for (int off = 32; off > 0; off >>= 1) sum += __shfl_down(sum, off);
        if (lane == 0) sc[t] = sum;
    }
    __syncthreads();
    if (wv == 0) {
        float v = (lane < s) ? sc[lane] : -3.0e38f;
        float m = v;
#pragma unroll
        for (int off = 32; off > 0; off >>= 1) m = fmaxf(m, __shfl_xor(m, off));
        float e = (lane < s) ? expf(v - m) : 0.f;
        float ss = e;
#pragma unroll
        for (int off = 32; off > 0; off >>= 1) ss += __shfl_xor(ss, off);
        if (lane < TT) sc[lane] = e / ss;
    }
    __syncthreads();
    for (int d = tid; d < DD; d += 256) {
        float sum = 0.f;
        for (int t = 0; t < s; ++t) sum += sc[t] * ref[((size_t)t * BB + b) * DD + d];
        ctx[b * DD + d] = sum;
    }
}

// ---------------- GEMM partial: out[b,d] partial over k-chunk -----------------
// cat = [A1(800) | A2(800)], W is [1600][800]. grid (25 d-tiles, 8 k-chunks of 200)
__global__ __launch_bounds__(256) void gemm_part_kernel(
    const float* __restrict__ A1, const float* __restrict__ A2,
    const float* __restrict__ W, float* __restrict__ pbuf)
{
    __shared__ float a_lds[BB][200];
    const int dt = blockIdx.x * 32;
    const int kc = blockIdx.y;
    const float* A = (kc < 4) ? A1 : A2;
    const int aoff = (kc < 4 ? kc : kc - 4) * 200;
    const int tid = threadIdx.x;
    for (int i = tid; i < BB * 200; i += 256) {
        int bb = i / 200, kk = i - bb * 200;
        a_lds[bb][kk] = A[bb * DD + aoff + kk];
    }
    __syncthreads();
    const int d = tid & 31;
    const int bq = tid >> 5;
    float acc[8] = {0, 0, 0, 0, 0, 0, 0, 0};
    const float* Wp = W + (size_t)(kc * 200) * DD + dt + d;
    for (int k = 0; k < 200; k += 4) {
        const float w0 = Wp[(k + 0) * DD];
        const float w1 = Wp[(k + 1) * DD];
        const float w2 = Wp[(k + 2) * DD];
        const float w3 = Wp[(k + 3) * DD];
#pragma unroll
        for (int i = 0; i < 8; ++i) {
            const float4 a4 = *reinterpret_cast<const float4*>(&a_lds[bq * 8 + i][k]);
            acc[i] = fmaf(a4.x, w0, fmaf(a4.y, w1, fmaf(a4.z, w2, fmaf(a4.w, w3, acc[i]))));
        }
    }
    float* pb = pbuf + (size_t)kc * (BB * DD) + dt + d;
#pragma unroll
    for (int i = 0; i < 8; ++i) pb[(bq * 8 + i) * DD] = acc[i];
}

// ---------------- reduce partials + bias + tanh, dual write -----------------
__global__ __launch_bounds__(256) void reduce_tanh_kernel(
    const float* __restrict__ pbuf, const float* __restrict__ bias,
    float* __restrict__ out1, float* __restrict__ out2)
{
    int i = blockIdx.x * 256 + threadIdx.x;
    if (i >= BB * DD) return;
    float sum = bias[i % DD];
#pragma unroll
    for (int kc = 0; kc < 8; ++kc) sum += pbuf[kc * (BB * DD) + i];
    float v = tanhf(sum);
    out1[i] = v;
    out2[i] = v;
}

__global__ __launch_bounds__(256) void copy2_kernel(
    const float* __restrict__ src, float* __restrict__ d1, float* __restrict__ d2)
{
    int i = blockIdx.x * 256 + threadIdx.x;
    if (i < BB * DD) {
        float v = src[i];
        d1[i] = v;
        d2[i] = v;
    }
}

// ---------------- head MLP: 4 batch rows per block -----------------
__global__ __launch_bounds__(256) void head_kernel(
    const float* __restrict__ hv,
    const float* __restrict__ w1, const float* __restrict__ b1,
    const float* __restrict__ w2, const float* __restrict__ b2,
    const float* __restrict__ w3, const float* __restrict__ b3,
    float* __restrict__ out, int s)
{
    __shared__ float h_lds[4][DD];
    __shared__ float v1[4][200];
    __shared__ float v2[4][52];
    const int tid = threadIdx.x;
    const int b0 = blockIdx.x * 4;
    for (int i = tid; i < 4 * DD; i += 256)
        h_lds[i / DD][i % DD] = hv[(b0 + i / DD) * DD + (i % DD)];
    __syncthreads();
    if (tid < 200) {
        float a0 = b1[tid], a1 = a0, a2 = a0, a3 = a0;
        for (int k = 0; k < DD; ++k) {
            float w = w1[k * 200 + tid];
            a0 = fmaf(h_lds[0][k], w, a0);
            a1 = fmaf(h_lds[1][k], w, a1);
            a2 = fmaf(h_lds[2][k], w, a2);
            a3 = fmaf(h_lds[3][k], w, a3);
        }
        v1[0][tid] = fmaxf(a0, 0.f);
        v1[1][tid] = fmaxf(a1, 0.f);
        v1[2][tid] = fmaxf(a2, 0.f);
        v1[3][tid] = fmaxf(a3, 0.f);
    }
    __syncthreads();
    if (tid < 50) {
        float a0 = b2[tid], a1 = a0, a2 = a0, a3 = a0;
        for (int k = 0; k < 200; ++k) {
            float w = w2[k * 50 + tid];
            a0 = fmaf(v1[0][k], w, a0);
            a1 = fmaf(v1[1][k], w, a1);
            a2 = fmaf(v1[2][k], w, a2);
            a3 = fmaf(v1[3][k], w, a3);
        }
        v2[0][tid] = fmaxf(a0, 0.f);
        v2[1][tid] = fmaxf(a1, 0.f);
        v2[2][tid] = fmaxf(a2, 0.f);
        v2[3][tid] = fmaxf(a3, 0.f);
    }
    __syncthreads();
    if (tid < 3) {
        float a[4] = {b3[tid], b3[tid], b3[tid], b3[tid]};
        for (int k = 0; k < 50; ++k) {
            float w = w3[k * 3 + tid];
#pragma unroll
            for (int i = 0; i < 4; ++i) a[i] = fmaf(v2[i][k], w, a[i]);
        }
#pragma unroll
        for (int i = 0; i < 4; ++i) out[((b0 + i) * TT + s) * 3 + tid] = a[i];
    }
}

extern "C" void kernel_launch(void* const* d_in, const int* in_sizes, int n_in,
                              void* d_out, int out_size, void* d_ws, size_t ws_size,
                              hipStream_t stream)
{
    const float* x_flat = (const float*)d_in[0];
    const float* enc    = (const float*)d_in[1];
    const float* init_h = (const float*)d_in[2];
    const float* init_c = (const float*)d_in[3];
    const float* conv_w[2] = {(const float*)d_in[4], (const float*)d_in[6]};
    const float* conv_b[2] = {(const float*)d_in[5], (const float*)d_in[7]};
    const float* iw[2] = {(const float*)d_in[8], (const float*)d_in[10]};
    const float* ibb[2] = {(const float*)d_in[9], (const float*)d_in[11]};
    const float* sw[2] = {(const float*)d_in[12], (const float*)d_in[14]};
    const float* sbb[2] = {(const float*)d_in[13], (const float*)d_in[15]};
    const float* hw1 = (const float*)d_in[16];
    const float* hb1 = (const float*)d_in[17];
    const float* hw2 = (const float*)d_in[18];
    const float* hb2 = (const float*)d_in[19];
    const float* hw3 = (const float*)d_in[20];
    const float* hb3 = (const float*)d_in[21];
    float* out = (float*)d_out;
    float* ws = (float*)d_ws;

    const size_t BD = (size_t)BB * DD; // 51200
    float* HP  = ws;                   // [2][51200]  h ping
    float* HQ  = HP + 2 * BD;          // [2][51200]  h pong
    float* CP  = HQ + 2 * BD;          // c ping
    float* CQ  = CP + 2 * BD;          // c pong
    float* PRE = CQ + 2 * BD;          // [2][32][64][800]
    float* REF = PRE + 2 * TT * BD;
    float* HV1 = REF + 2 * TT * BD;    // post-inter state [B,D]
    float* CTX = HV1 + BD;             // attention context [B,D]
    float* LIO = CTX + BD;             // layer output / next-layer input [B,D]
    float* PBUF = LIO + BD;            // GEMM partials [8][B*D]

    hipMemcpyAsync(HP, init_h, 2 * BD * sizeof(float), hipMemcpyDeviceToDevice, stream);
    hipMemcpyAsync(CP, init_c, 2 * BD * sizeof(float), hipMemcpyDeviceToDevice, stream);

    for (int s = 0; s < TT; ++s) {
        float* hsrc = (s & 1) ? HQ : HP;
        float* hdst = (s & 1) ? HP : HQ;
        float* csrc = (s & 1) ? CQ : CP;
        float* cdst = (s & 1) ? CP : CQ;
        for (int l = 0; l < 2; ++l) {
            const float* xin = (l == 0) ? x_flat : LIO;
            int cin_x = (l == 0) ? 1 : 8;
            float* h_new = hdst + (size_t)l * BD;
            float* c_new = cdst + (size_t)l * BD;
            cell_kernel<<<200, 256, 0, stream>>>(xin, s, cin_x,
                                                 hsrc + (size_t)l * BD, csrc + (size_t)l * BD,
                                                 h_new, c_new, conv_w[l], conv_b[l]);
            inter_attn_kernel<<<64, 256, 0, stream>>>(h_new, enc, CTX);
            gemm_part_kernel<<<dim3(25, 8), 256, 0, stream>>>(CTX, h_new, iw[l], PBUF);
            reduce_tanh_kernel<<<200, 256, 0, stream>>>(PBUF, ibb[l], HV1,
                                                        PRE + (size_t)(l * TT + s) * BD);
            if (s == 0) {
                copy2_kernel<<<200, 256, 0, stream>>>(HV1, LIO, REF + (size_t)(l * TT) * BD);
            } else {
                self_attn_kernel<<<64, 256, 0, stream>>>(HV1, PRE + (size_t)l * TT * BD,
                                                         REF + (size_t)l * TT * BD, s, CTX);
                gemm_part_kernel<<<dim3(25, 8), 256, 0, stream>>>(CTX, HV1, sw[l], PBUF);
                reduce_tanh_kernel<<<200, 256, 0, stream>>>(PBUF, sbb[l], LIO,
                                                            REF + (size_t)(l * TT + s) * BD);
            }
        }
        head_kernel<<<16, 256, 0, stream>>>(LIO, hw1, hb1, hw2, hb2, hw3, hb3, out, s);
    }
}